// Round 7
// baseline (747.066 us; speedup 1.0000x reference)
//
#include <hip/hip_runtime.h>
#include <hip/hip_bf16.h>
#include <stdint.h>

typedef float f32x4 __attribute__((ext_vector_type(4)));
typedef short bf16x8 __attribute__((ext_vector_type(8)));

#define NSLOT 16                 // row-slot groups
#define NDS 24                   // gate-dim slices per slot
#define NBLK (NSLOT * NDS)       // 384 blocks, 2/CU -> all co-resident
// counters: 720 step-barriers (5 lvl x 9 idx x 16 slot) + 64 boundary-group + 4 boundary-master
#define NCTR 788
#define CI(i) ((i) * 32)   // pad counters to separate 128B lines

__device__ __forceinline__ ushort to_bf16(float f) {
    union { float f; uint32_t u; } v; v.f = f;
    uint32_t u = v.u;
    return (ushort)((u + 0x7fffu + ((u >> 16) & 1u)) >> 16);   // RNE
}
__device__ __forceinline__ float sigmoid_(float x) { return 1.0f / (1.0f + __expf(-x)); }
__device__ __forceinline__ float tanh_(float x)    { return 1.0f - 2.0f / (__expf(2.0f * x) + 1.0f); }

// Device-scope write-through stores: land at the Infinity Cache coherence
// point, leave no dirty L2 line behind. (Proven in rounds 2/5/6.)
__device__ __forceinline__ void st_sc1_u16(ushort* p, ushort v) {
    asm volatile("global_store_short %0, %1, off sc1" :: "v"(p), "v"((uint32_t)v) : "memory");
}
__device__ __forceinline__ void st_sc1_f32(float* p, float v) {
    asm volatile("global_store_dword %0, %1, off sc1" :: "v"(p), "v"(v) : "memory");
}
__device__ __forceinline__ void st_sc1_b128(void* p, bf16x8 v) {
    asm volatile("global_store_dwordx4 %0, %1, off sc1" :: "v"(p), "v"(v) : "memory");
}

// Swizzled concat weight W'[g][k] = (k<384 ? w_ih : w_hh), bf16; fragment layout:
// elem ((tile*24 + kc)*64 + quad*16 + (g&15))*8 + j  for k = kc*32 + quad*8 + j
__global__ void prep_w(const float* __restrict__ w_ih, const float* __restrict__ w_hh,
                       ushort* __restrict__ wswz, unsigned int* __restrict__ ctr) {
    int tid = blockIdx.x * blockDim.x + threadIdx.x;   // 1152 * 96
    if (tid < NCTR * 32) ctr[tid] = 0u;                // re-zero barrier counters each replay
    if (tid >= 1152 * 96) return;
    int g  = tid / 96;
    int k  = (tid % 96) * 8;
    int kc = k >> 5;
    int q  = (k >> 3) & 3;
    int tile = g >> 4;
    int lane = q * 16 + (g & 15);
    ushort* dst = wswz + ((size_t)(tile * 24 + kc) * 64 + lane) * 8;
    const float* src = (k < 384) ? (w_ih + (size_t)g * 384 + k)
                                 : (w_hh + (size_t)g * 384 + (k - 384));
#pragma unroll
    for (int j = 0; j < 8; ++j) dst[j] = to_bf16(src[j]);
}

__global__ void embed_gather(const int* __restrict__ tok, const float* __restrict__ table,
                             ushort* __restrict__ xleaf, int n_leaves) {
    int tid = blockIdx.x * blockDim.x + threadIdx.x;   // n_leaves * 48
    if (tid >= n_leaves * 48) return;
    int leaf = tid / 48, i = tid % 48;
    const float* src = table + (size_t)tok[leaf] * 384 + i * 8;
    bf16x8 v;
#pragma unroll
    for (int j = 0; j < 8; ++j) v[j] = (short)to_bf16(src[j]);
    *(bf16x8*)(xleaf + (size_t)leaf * 384 + i * 8) = v;
}

// Poll by atomic fetch_add(0): an agent-scope RMW must execute at the
// coherence point, so it returns the EXACT current value every poll —
// no stale private cache copy possible (relaxed atomic LOADS proved to
// serve stale data for ~10+ us; see rounds 2/5/6 invariance).
__device__ __forceinline__ void wait_ge(unsigned int* c, unsigned int n) {
    while (__hip_atomic_fetch_add(c, 0u, __ATOMIC_RELAXED, __HIP_MEMORY_SCOPE_AGENT) < n) {}
}

// Group barrier among the 24 ds-blocks of one row-slot, split into arrive /
// wait so independent work (next-step x loads + x-half MFMAs) runs inside
// the wait window.
__device__ __forceinline__ void group_arrive(unsigned int* c) {
    __syncthreads();   // drains vmcnt: all waves' sc1 h-stores committed
    if (threadIdx.x == 0)
        __hip_atomic_fetch_add(c, 1u, __ATOMIC_RELEASE, __HIP_MEMORY_SCOPE_AGENT);
}
__device__ __forceinline__ void group_wait(unsigned int* c) {
    if (threadIdx.x == 0) wait_ge(c, NDS);
    __syncthreads();
}

// Hierarchical full-grid barrier (384 blocks): 24 arrivals per slot-group,
// last of each group bumps master; everyone polls (RMW) on master == NSLOT.
__device__ __forceinline__ void full_barrier(unsigned int* grpSlot, unsigned int* master) {
    __syncthreads();
    if (threadIdx.x == 0) {
        unsigned int old = __hip_atomic_fetch_add(grpSlot, 1u, __ATOMIC_RELEASE, __HIP_MEMORY_SCOPE_AGENT);
        if (old == NDS - 1)
            __hip_atomic_fetch_add(master, 1u, __ATOMIC_RELEASE, __HIP_MEMORY_SCOPE_AGENT);
        wait_ge(master, NSLOT);
    }
    __syncthreads();
}

// One persistent kernel for the whole tree. 384 blocks x 256 thr, ~78 KB LDS
// -> 2 blocks/CU, all co-resident. Block l: slot = (l&7)*2 + (l>>3)/24,
// ds = (l>>3)%24 -> under round-robin dispatch (xcd = l%8) all 24 ds-blocks
// of a slot land on ONE XCD (verified round 6: FETCH_SIZE 243->49 MB).
// Slot owns m-pairs slot*4+wave (+64). h_prev / running sum in registers;
// bf16 h exchanged via per-step FRESH buffers (no stale cache copies).
__global__ __launch_bounds__(256, 2)
void tree_gru(const ushort* __restrict__ XA, const ushort* __restrict__ W,
              const float* __restrict__ b_ih, const float* __restrict__ b_hh,
              ushort* __restrict__ HBar, float* __restrict__ Hfar,
              ushort* __restrict__ Xoar,
              unsigned int* __restrict__ ctr, float* __restrict__ out)
{
    __shared__ __align__(16) ushort lw[36864];     // weight slice, 72 KB
    __shared__ __align__(16) ushort stage[4][768]; // h-transpose staging, 6 KB (24-stride)
    const int l = blockIdx.x;
    const int dr = l >> 3;                  // 0..47
    const int slot = (l & 7) * 2 + (dr / 24);
    const int ds = dr % 24;
    const int tid = threadIdx.x;
    const int wave = tid >> 6, lane = tid & 63;
    const int quad = lane >> 4, col = lane & 15;
    const int d = ds * 16 + col;

    // Stage this block's weight slice (tiles ds, 24+ds, 48+ds) into LDS - once
    // for the whole tree (all steps, all levels).
    {
        bf16x8* dstv = (bf16x8*)lw;
#pragma unroll
        for (int g = 0; g < 3; ++g) {
            const bf16x8* s = (const bf16x8*)(W + (size_t)(g * NDS + ds) * 12288);
#pragma unroll
            for (int i = 0; i < 6; ++i) dstv[g * 1536 + i * 256 + tid] = s[i * 256 + tid];
        }
    }
    __syncthreads();

    const float br = b_ih[d] + b_hh[d];
    const float bz = b_ih[384 + d] + b_hh[384 + d];
    const float bi = b_ih[768 + d], bh = b_hh[768 + d];
    const ushort* lwr = &lw[(size_t)lane * 8];

#pragma unroll 1
    for (int lvl = 0; lvl < 5; ++lvl) {
        const int P  = (lvl == 0) ? 4096 : (lvl == 1) ? 512 : (lvl == 2) ? 64 : (lvl == 3) ? 8 : 1;
        const int rp = (lvl == 0) ? 0 : (lvl == 1) ? 4096 : (lvl == 2) ? 4608 : (lvl == 3) ? 4672 : 4680;
        const int rpPrev = (lvl == 1) ? 0 : (lvl == 2) ? 4096 : (lvl == 3) ? 4608 : 4672;
        const int nmp = (P + 31) >> 5;          // 32-row m-pairs
        const bool leaf = (lvl == 0), root = (lvl == 4);
        const ushort* Xc = leaf ? XA : (Xoar + (size_t)384 * rpPrev);
        const float* Hfprev = leaf ? nullptr : (Hfar + (size_t)384 * rpPrev);
        ushort* HBlvl = HBar + (size_t)9 * 384 * rp;   // 9 fresh h slots this level
        ushort* Xout  = Xoar + (size_t)384 * rp;
        float*  Hfout = root ? nullptr : (Hfar + (size_t)384 * rp);
        const size_t N = (size_t)P * 384;
        const bool act = (slot * 4 < nmp);             // uniform per slot-group
        if (act) {
            const int mpA = slot * 4 + wave;
            const int mpB = mpA + NSLOT * 4;
            const bool hasA = mpA < nmp;
            const bool hasB = mpB < nmp;
            float hpA[2][4], hsA[2][4], hpB[2][4], hsB[2][4];
#pragma unroll
            for (int mt = 0; mt < 2; ++mt)
#pragma unroll
                for (int r = 0; r < 4; ++r) {
                    hpA[mt][r] = 0.f; hsA[mt][r] = 0.f;
                    hpB[mt][r] = 0.f; hsB[mt][r] = 0.f;
                }
            const f32x4 z4 = (f32x4){0.f, 0.f, 0.f, 0.f};
            const bf16x8 zf = (bf16x8){0, 0, 0, 0, 0, 0, 0, 0};
            struct XA6 { f32x4 r[2], z[2], n[2]; } xA, xB;

            // x-half MFMAs (independent of h) — runs inside barrier-wait windows.
            auto xpart = [&](int mp, int child, XA6& o) {
                const int m0 = mp * 32;
                const bool do2 = (m0 + 16) < P;
                const int par0 = m0 + col, par1 = m0 + 16 + col;
                const bool av0 = par0 < P, av1 = par1 < P;
                const ushort* xr0 = Xc + ((size_t)par0 * 8 + child) * 384 + quad * 8;
                const ushort* xr1 = Xc + ((size_t)par1 * 8 + child) * 384 + quad * 8;
                o.r[0] = z4; o.z[0] = z4; o.n[0] = z4;
                o.r[1] = z4; o.z[1] = z4; o.n[1] = z4;
#pragma unroll
                for (int kc = 0; kc < 12; ++kc) {
                    bf16x8 a0 = zf, a1 = zf;
                    if (av0) a0 = *(const bf16x8*)(xr0 + kc * 32);
                    if (do2 && av1) a1 = *(const bf16x8*)(xr1 + kc * 32);
                    bf16x8 bR = *(const bf16x8*)(lwr + kc * 512);
                    bf16x8 bZ = *(const bf16x8*)(lwr + 12288 + kc * 512);
                    bf16x8 bN = *(const bf16x8*)(lwr + 24576 + kc * 512);
                    o.r[0] = __builtin_amdgcn_mfma_f32_16x16x32_bf16(a0, bR, o.r[0], 0, 0, 0);
                    o.z[0] = __builtin_amdgcn_mfma_f32_16x16x32_bf16(a0, bZ, o.z[0], 0, 0, 0);
                    o.n[0] = __builtin_amdgcn_mfma_f32_16x16x32_bf16(a0, bN, o.n[0], 0, 0, 0);
                    if (do2) {
                        o.r[1] = __builtin_amdgcn_mfma_f32_16x16x32_bf16(a1, bR, o.r[1], 0, 0, 0);
                        o.z[1] = __builtin_amdgcn_mfma_f32_16x16x32_bf16(a1, bZ, o.z[1], 0, 0, 0);
                        o.n[1] = __builtin_amdgcn_mfma_f32_16x16x32_bf16(a1, bN, o.n[1], 0, 0, 0);
                    }
                }
            };
            // h0 = mean of children's final h; publish bf16 to slot 0.
            auto prol = [&](int mp, float (&hp)[2][4]) {
                const int m0 = mp * 32;
#pragma unroll
                for (int mt = 0; mt < 2; ++mt)
#pragma unroll
                    for (int r = 0; r < 4; ++r) {
                        const int m = m0 + mt * 16 + quad * 4 + r;
                        if (m < P) {
                            const float* hc = Hfprev + (size_t)m * 8 * 384 + d;
                            float h0 = 0.f;
#pragma unroll
                            for (int c = 0; c < 8; ++c) h0 += hc[(size_t)c * 384];
                            h0 *= 0.125f;
                            hp[mt][r] = h0;
                            st_sc1_u16(&HBlvl[(size_t)m * 384 + d], to_bf16(h0));
                        }
                    }
            };
            // h-half MFMAs + gate update + vectorized h publish via LDS transpose.
            auto hpart = [&](int mp, XA6& x, float (&hp)[2][4], float (&hs)[2][4],
                             const ushort* HBp, ushort* HBn, bool hz, bool last) {
                const int m0 = mp * 32;
                const bool do2 = (m0 + 16) < P;
                const int par0 = m0 + col, par1 = m0 + 16 + col;
                const bool av0 = par0 < P, av1 = par1 < P;
                f32x4 n2a = z4, n2b = z4;
                if (!hz) {
                    const ushort* hr0 = HBp + (size_t)par0 * 384 + quad * 8;
                    const ushort* hr1 = HBp + (size_t)par1 * 384 + quad * 8;
#pragma unroll
                    for (int kc = 0; kc < 12; ++kc) {
                        bf16x8 a0 = zf, a1 = zf;
                        if (av0) a0 = *(const bf16x8*)(hr0 + kc * 32);
                        if (do2 && av1) a1 = *(const bf16x8*)(hr1 + kc * 32);
                        bf16x8 bR = *(const bf16x8*)(lwr + (12 + kc) * 512);
                        bf16x8 bZ = *(const bf16x8*)(lwr + 12288 + (12 + kc) * 512);
                        bf16x8 bN = *(const bf16x8*)(lwr + 24576 + (12 + kc) * 512);
                        x.r[0] = __builtin_amdgcn_mfma_f32_16x16x32_bf16(a0, bR, x.r[0], 0, 0, 0);
                        x.z[0] = __builtin_amdgcn_mfma_f32_16x16x32_bf16(a0, bZ, x.z[0], 0, 0, 0);
                        n2a    = __builtin_amdgcn_mfma_f32_16x16x32_bf16(a0, bN, n2a, 0, 0, 0);
                        if (do2) {
                            x.r[1] = __builtin_amdgcn_mfma_f32_16x16x32_bf16(a1, bR, x.r[1], 0, 0, 0);
                            x.z[1] = __builtin_amdgcn_mfma_f32_16x16x32_bf16(a1, bZ, x.z[1], 0, 0, 0);
                            n2b    = __builtin_amdgcn_mfma_f32_16x16x32_bf16(a1, bN, n2b, 0, 0, 0);
                        }
                    }
                }
#pragma unroll
                for (int mt = 0; mt < 2; ++mt) {
                    if (mt && !do2) break;
                    const f32x4 ar = x.r[mt], az = x.z[mt], an1 = x.n[mt];
                    const f32x4 an2 = mt ? n2b : n2a;
#pragma unroll
                    for (int r = 0; r < 4; ++r) {
                        const int m = m0 + mt * 16 + quad * 4 + r;
                        if (m < P) {
                            float rv = sigmoid_(ar[r] + br);
                            float zv = sigmoid_(az[r] + bz);
                            float nv = tanh_(an1[r] + bi + rv * (an2[r] + bh));
                            float hn = (1.0f - zv) * nv + zv * hp[mt][r];
                            hp[mt][r] = hn;
                            hs[mt][r] += hn;
                            if (last) {
                                const size_t idx = (size_t)m * 384 + d;
                                float xo = hs[mt][r] * 0.125f;
                                st_sc1_u16(&Xout[idx], to_bf16(xo));
                                if (!root) st_sc1_f32(&Hfout[idx], hn);
                                else if (m == 0) out[d] = xo;
                            } else {
                                stage[wave][(mt * 16 + quad * 4 + r) * 24 + col] = to_bf16(hn);
                            }
                        }
                    }
                }
                if (!last) {   // wave-private transpose -> one 16B sc1 store per lane
                    const int row = lane >> 1, half = lane & 1;
                    const int m = m0 + row;
                    if (m < P) {
                        bf16x8 v = *(const bf16x8*)&stage[wave][row * 24 + half * 8];
                        st_sc1_b128(HBn + (size_t)m * 384 + ds * 16 + half * 8, v);
                    }
                }
            };

            if (!leaf) {
                if (hasA) prol(mpA, hpA);
                if (hasB) prol(mpB, hpB);
                group_arrive(&ctr[CI((lvl * 9 + 8) * NSLOT + slot)]);
                if (hasA) xpart(mpA, 7, xA);     // t=0 x-half under the barrier
                if (hasB) xpart(mpB, 7, xB);
                group_wait(&ctr[CI((lvl * 9 + 8) * NSLOT + slot)]);
            } else {
                if (hasA) xpart(mpA, 7, xA);
                if (hasB) xpart(mpB, 7, xB);
            }
#pragma unroll 1
            for (int t = 0; t < 8; ++t) {
                const ushort* HBp = HBlvl + (size_t)t * N;
                ushort*       HBn = HBlvl + (size_t)(t + 1) * N;
                const bool hz   = leaf && (t == 0);
                const bool last = (t == 7);
                if (hasA) hpart(mpA, xA, hpA, hsA, HBp, HBn, hz, last);
                if (hasB) hpart(mpB, xB, hpB, hsB, HBp, HBn, hz, last);
                if (!last) {
                    unsigned int* c = &ctr[CI((lvl * 9 + t) * NSLOT + slot)];
                    group_arrive(c);
                    const int nchild = 6 - t;    // next step's x-half under the barrier
                    if (hasA) xpart(mpA, nchild, xA);
                    if (hasB) xpart(mpB, nchild, xB);
                    group_wait(c);
                }
            }
        }
        if (lvl < 4) full_barrier(&ctr[CI(720 + lvl * NSLOT + slot)], &ctr[CI(784 + lvl)]);
    }
}

extern "C" void kernel_launch(void* const* d_in, const int* in_sizes, int n_in,
                              void* d_out, int out_size, void* d_ws, size_t ws_size,
                              hipStream_t stream) {
    const int*   tok   = (const int*)d_in[0];
    const float* table = (const float*)d_in[1];
    const float* w_ih  = (const float*)d_in[2];
    const float* w_hh  = (const float*)d_in[3];
    const float* b_ih  = (const float*)d_in[4];
    const float* b_hh  = (const float*)d_in[5];
    float* out = (float*)d_out;

    char* ws = (char*)d_ws;
    size_t off = 0;
    auto alloc = [&](size_t bytes) -> void* {
        void* p = ws + off;
        off = (off + bytes + 255) & ~(size_t)255;
        return p;
    };
    // total rows across levels: 4096+512+64+8+1 = 4681
    ushort* wswz = (ushort*)alloc((size_t)1152 * 768 * 2);      // swizzled weights
    ushort* XA   = (ushort*)alloc((size_t)32768 * 384 * 2);     // leaf x (bf16)
    ushort* HBar = (ushort*)alloc((size_t)9 * 4681 * 384 * 2);  // per-level 9 fresh h slots
    float*  Hfar = (float*)alloc((size_t)4680 * 384 * 4);       // per-level final h (lvl 0..3)
    ushort* Xoar = (ushort*)alloc((size_t)4681 * 384 * 2);      // per-level output x
    unsigned int* ctr = (unsigned int*)alloc((size_t)NCTR * 32 * 4);

    prep_w<<<(1152 * 96 + 255) / 256, 256, 0, stream>>>(w_ih, w_hh, wswz, ctr);
    embed_gather<<<(32768 * 48 + 255) / 256, 256, 0, stream>>>(tok, table, XA, 32768);
    tree_gru<<<dim3(NBLK), 256, 0, stream>>>(XA, wswz, b_ih, b_hh,
                                             HBar, Hfar, Xoar, ctr, out);
}

// Round 9
// 634.852 us; speedup vs baseline: 1.1768x; 1.1768x over previous
//
#include <hip/hip_runtime.h>
#include <hip/hip_bf16.h>
#include <stdint.h>

typedef float f32x4 __attribute__((ext_vector_type(4)));
typedef short bf16x8 __attribute__((ext_vector_type(8)));

#define NSLOT 16                 // row-slot groups
#define NDS 24                   // gate-dim slices per slot
#define NBLK (NSLOT * NDS)       // 384 blocks, 2/CU -> all co-resident
// counters: 720 step-barriers (5 lvl x 9 idx x 16 slot) + 64 boundary-group + 4 boundary-master
#define NCTR 788
#define CI(i) ((i) * 32)   // pad counters to separate 128B lines

__device__ __forceinline__ ushort to_bf16(float f) {
    union { float f; uint32_t u; } v; v.f = f;
    uint32_t u = v.u;
    return (ushort)((u + 0x7fffu + ((u >> 16) & 1u)) >> 16);   // RNE
}
__device__ __forceinline__ float sigmoid_(float x) { return 1.0f / (1.0f + __expf(-x)); }
__device__ __forceinline__ float tanh_(float x)    { return 1.0f - 2.0f / (__expf(2.0f * x) + 1.0f); }

// Device-scope write-through stores: land at the Infinity Cache coherence
// point, leave no dirty L2 line behind. (Proven in rounds 2/5/6/7.)
__device__ __forceinline__ void st_sc1_u16(ushort* p, ushort v) {
    asm volatile("global_store_short %0, %1, off sc1" :: "v"(p), "v"((uint32_t)v) : "memory");
}
__device__ __forceinline__ void st_sc1_f32(float* p, float v) {
    asm volatile("global_store_dword %0, %1, off sc1" :: "v"(p), "v"(v) : "memory");
}
__device__ __forceinline__ void st_sc1_b128(void* p, bf16x8 v) {
    asm volatile("global_store_dwordx4 %0, %1, off sc1" :: "v"(p), "v"(v) : "memory");
}

// Swizzled concat weight W'[g][k] = (k<384 ? w_ih : w_hh), bf16; fragment layout:
// elem ((tile*24 + kc)*64 + quad*16 + (g&15))*8 + j  for k = kc*32 + quad*8 + j
__global__ void prep_w(const float* __restrict__ w_ih, const float* __restrict__ w_hh,
                       ushort* __restrict__ wswz, unsigned int* __restrict__ ctr) {
    int tid = blockIdx.x * blockDim.x + threadIdx.x;   // 1152 * 96
    if (tid < NCTR * 32) ctr[tid] = 0u;                // re-zero barrier counters each replay
    if (tid >= 1152 * 96) return;
    int g  = tid / 96;
    int k  = (tid % 96) * 8;
    int kc = k >> 5;
    int q  = (k >> 3) & 3;
    int tile = g >> 4;
    int lane = q * 16 + (g & 15);
    ushort* dst = wswz + ((size_t)(tile * 24 + kc) * 64 + lane) * 8;
    const float* src = (k < 384) ? (w_ih + (size_t)g * 384 + k)
                                 : (w_hh + (size_t)g * 384 + (k - 384));
#pragma unroll
    for (int j = 0; j < 8; ++j) dst[j] = to_bf16(src[j]);
}

__global__ void embed_gather(const int* __restrict__ tok, const float* __restrict__ table,
                             ushort* __restrict__ xleaf, int n_leaves) {
    int tid = blockIdx.x * blockDim.x + threadIdx.x;   // n_leaves * 48
    if (tid >= n_leaves * 48) return;
    int leaf = tid / 48, i = tid % 48;
    const float* src = table + (size_t)tok[leaf] * 384 + i * 8;
    bf16x8 v;
#pragma unroll
    for (int j = 0; j < 8; ++j) v[j] = (short)to_bf16(src[j]);
    *(bf16x8*)(xleaf + (size_t)leaf * 384 + i * 8) = v;
}

// Poll by atomic fetch_add(0): executes at the coherence point, returns the
// exact current value every poll (proven r7: no staleness possible).
// s_sleep(1) between failed polls keeps fabric pressure bounded during long
// waits (e.g. inactive slots parked at level boundaries).
__device__ __forceinline__ void wait_ge(unsigned int* c, unsigned int n) {
    while (__hip_atomic_fetch_add(c, 0u, __ATOMIC_RELAXED, __HIP_MEMORY_SCOPE_AGENT) < n)
        __builtin_amdgcn_s_sleep(1);
}

// Group barrier among the 24 ds-blocks of one row-slot, split into arrive /
// wait so independent work (next-step x loads + x-half MFMAs) runs inside
// the wait window.
// KEY CHANGE (r8/r9): arrive RMW is RELAXED, not RELEASE. An agent-scope
// release emits buffer_wbl2 (full 4MiB L2 tag walk) on gfx950 — suspected
// fixed ~10us/step cost common to ALL prior rounds AND the multi-launch
// baseline (end-of-kernel release). Ordering without the fence: the
// __syncthreads() drains vmcnt(0); sc1 write-through stores retire vmcnt
// only when ACK'd at the IF coherence point -> all h-lines are globally
// visible before the flag bump. No dirty L2 lines exist (all cross-block
// stores are sc1), so the writeback walk buys nothing.
__device__ __forceinline__ void group_arrive(unsigned int* c) {
    __syncthreads();   // s_waitcnt vmcnt(0) lgkmcnt(0) + s_barrier
    if (threadIdx.x == 0)
        __hip_atomic_fetch_add(c, 1u, __ATOMIC_RELAXED, __HIP_MEMORY_SCOPE_AGENT);
}
__device__ __forceinline__ void group_wait(unsigned int* c) {
    if (threadIdx.x == 0) wait_ge(c, NDS);
    __syncthreads();
}

// Hierarchical full-grid barrier (384 blocks): 24 arrivals per slot-group,
// last of each group bumps master; everyone polls (RMW) on master == NSLOT.
// Keeps RELEASE (4 occurrences total — cross-level safety, negligible cost).
__device__ __forceinline__ void full_barrier(unsigned int* grpSlot, unsigned int* master) {
    __syncthreads();
    if (threadIdx.x == 0) {
        unsigned int old = __hip_atomic_fetch_add(grpSlot, 1u, __ATOMIC_RELEASE, __HIP_MEMORY_SCOPE_AGENT);
        if (old == NDS - 1)
            __hip_atomic_fetch_add(master, 1u, __ATOMIC_RELEASE, __HIP_MEMORY_SCOPE_AGENT);
        wait_ge(master, NSLOT);
    }
    __syncthreads();
}

// One persistent kernel for the whole tree. 384 blocks x 256 thr, ~78 KB LDS
// -> 2 blocks/CU, all co-resident. Block l: slot = (l&7)*2 + (l>>3)/24,
// ds = (l>>3)%24 -> under round-robin dispatch (xcd = l%8) all 24 ds-blocks
// of a slot land on ONE XCD (verified round 6: FETCH_SIZE 243->49 MB).
// Slot owns m-pairs slot*4+wave (+64). h_prev / running sum in registers;
// bf16 h exchanged via per-step FRESH buffers (no stale cache copies).
__global__ __launch_bounds__(256, 2)
void tree_gru(const ushort* __restrict__ XA, const ushort* __restrict__ W,
              const float* __restrict__ b_ih, const float* __restrict__ b_hh,
              ushort* __restrict__ HBar, float* __restrict__ Hfar,
              ushort* __restrict__ Xoar,
              unsigned int* __restrict__ ctr, float* __restrict__ out)
{
    __shared__ __align__(16) ushort lw[36864];     // weight slice, 72 KB
    __shared__ __align__(16) ushort stage[4][768]; // h-transpose staging, 6 KB (24-stride)
    const int l = blockIdx.x;
    const int dr = l >> 3;                  // 0..47
    const int slot = (l & 7) * 2 + (dr / 24);
    const int ds = dr % 24;
    const int tid = threadIdx.x;
    const int wave = tid >> 6, lane = tid & 63;
    const int quad = lane >> 4, col = lane & 15;
    const int d = ds * 16 + col;

    // Stage this block's weight slice (tiles ds, 24+ds, 48+ds) into LDS - once
    // for the whole tree (all steps, all levels).
    {
        bf16x8* dstv = (bf16x8*)lw;
#pragma unroll
        for (int g = 0; g < 3; ++g) {
            const bf16x8* s = (const bf16x8*)(W + (size_t)(g * NDS + ds) * 12288);
#pragma unroll
            for (int i = 0; i < 6; ++i) dstv[g * 1536 + i * 256 + tid] = s[i * 256 + tid];
        }
    }
    __syncthreads();

    const float br = b_ih[d] + b_hh[d];
    const float bz = b_ih[384 + d] + b_hh[384 + d];
    const float bi = b_ih[768 + d], bh = b_hh[768 + d];
    const ushort* lwr = &lw[(size_t)lane * 8];

#pragma unroll 1
    for (int lvl = 0; lvl < 5; ++lvl) {
        const int P  = (lvl == 0) ? 4096 : (lvl == 1) ? 512 : (lvl == 2) ? 64 : (lvl == 3) ? 8 : 1;
        const int rp = (lvl == 0) ? 0 : (lvl == 1) ? 4096 : (lvl == 2) ? 4608 : (lvl == 3) ? 4672 : 4680;
        const int rpPrev = (lvl == 1) ? 0 : (lvl == 2) ? 4096 : (lvl == 3) ? 4608 : 4672;
        const int nmp = (P + 31) >> 5;          // 32-row m-pairs
        const bool leaf = (lvl == 0), root = (lvl == 4);
        const ushort* Xc = leaf ? XA : (Xoar + (size_t)384 * rpPrev);
        const float* Hfprev = leaf ? nullptr : (Hfar + (size_t)384 * rpPrev);
        ushort* HBlvl = HBar + (size_t)9 * 384 * rp;   // 9 fresh h slots this level
        ushort* Xout  = Xoar + (size_t)384 * rp;
        float*  Hfout = root ? nullptr : (Hfar + (size_t)384 * rp);
        const size_t N = (size_t)P * 384;
        const bool act = (slot * 4 < nmp);             // uniform per slot-group
        if (act) {
            const int mpA = slot * 4 + wave;
            const int mpB = mpA + NSLOT * 4;
            const bool hasA = mpA < nmp;
            const bool hasB = mpB < nmp;
            float hpA[2][4], hsA[2][4], hpB[2][4], hsB[2][4];
#pragma unroll
            for (int mt = 0; mt < 2; ++mt)
#pragma unroll
                for (int r = 0; r < 4; ++r) {
                    hpA[mt][r] = 0.f; hsA[mt][r] = 0.f;
                    hpB[mt][r] = 0.f; hsB[mt][r] = 0.f;
                }
            const f32x4 z4 = (f32x4){0.f, 0.f, 0.f, 0.f};
            const bf16x8 zf = (bf16x8){0, 0, 0, 0, 0, 0, 0, 0};
            struct XA6 { f32x4 r[2], z[2], n[2]; } xA, xB;

            // x-half MFMAs (independent of h) — runs inside barrier-wait windows.
            auto xpart = [&](int mp, int child, XA6& o) {
                const int m0 = mp * 32;
                const bool do2 = (m0 + 16) < P;
                const int par0 = m0 + col, par1 = m0 + 16 + col;
                const bool av0 = par0 < P, av1 = par1 < P;
                const ushort* xr0 = Xc + ((size_t)par0 * 8 + child) * 384 + quad * 8;
                const ushort* xr1 = Xc + ((size_t)par1 * 8 + child) * 384 + quad * 8;
                o.r[0] = z4; o.z[0] = z4; o.n[0] = z4;
                o.r[1] = z4; o.z[1] = z4; o.n[1] = z4;
#pragma unroll
                for (int kc = 0; kc < 12; ++kc) {
                    bf16x8 a0 = zf, a1 = zf;
                    if (av0) a0 = *(const bf16x8*)(xr0 + kc * 32);
                    if (do2 && av1) a1 = *(const bf16x8*)(xr1 + kc * 32);
                    bf16x8 bR = *(const bf16x8*)(lwr + kc * 512);
                    bf16x8 bZ = *(const bf16x8*)(lwr + 12288 + kc * 512);
                    bf16x8 bN = *(const bf16x8*)(lwr + 24576 + kc * 512);
                    o.r[0] = __builtin_amdgcn_mfma_f32_16x16x32_bf16(a0, bR, o.r[0], 0, 0, 0);
                    o.z[0] = __builtin_amdgcn_mfma_f32_16x16x32_bf16(a0, bZ, o.z[0], 0, 0, 0);
                    o.n[0] = __builtin_amdgcn_mfma_f32_16x16x32_bf16(a0, bN, o.n[0], 0, 0, 0);
                    if (do2) {
                        o.r[1] = __builtin_amdgcn_mfma_f32_16x16x32_bf16(a1, bR, o.r[1], 0, 0, 0);
                        o.z[1] = __builtin_amdgcn_mfma_f32_16x16x32_bf16(a1, bZ, o.z[1], 0, 0, 0);
                        o.n[1] = __builtin_amdgcn_mfma_f32_16x16x32_bf16(a1, bN, o.n[1], 0, 0, 0);
                    }
                }
            };
            // h0 = mean of children's final h; publish bf16 to slot 0.
            auto prol = [&](int mp, float (&hp)[2][4]) {
                const int m0 = mp * 32;
#pragma unroll
                for (int mt = 0; mt < 2; ++mt)
#pragma unroll
                    for (int r = 0; r < 4; ++r) {
                        const int m = m0 + mt * 16 + quad * 4 + r;
                        if (m < P) {
                            const float* hc = Hfprev + (size_t)m * 8 * 384 + d;
                            float h0 = 0.f;
#pragma unroll
                            for (int c = 0; c < 8; ++c) h0 += hc[(size_t)c * 384];
                            h0 *= 0.125f;
                            hp[mt][r] = h0;
                            st_sc1_u16(&HBlvl[(size_t)m * 384 + d], to_bf16(h0));
                        }
                    }
            };
            // h-half MFMAs + gate update + vectorized h publish via LDS transpose.
            auto hpart = [&](int mp, XA6& x, float (&hp)[2][4], float (&hs)[2][4],
                             const ushort* HBp, ushort* HBn, bool hz, bool last) {
                const int m0 = mp * 32;
                const bool do2 = (m0 + 16) < P;
                const int par0 = m0 + col, par1 = m0 + 16 + col;
                const bool av0 = par0 < P, av1 = par1 < P;
                f32x4 n2a = z4, n2b = z4;
                if (!hz) {
                    const ushort* hr0 = HBp + (size_t)par0 * 384 + quad * 8;
                    const ushort* hr1 = HBp + (size_t)par1 * 384 + quad * 8;
#pragma unroll
                    for (int kc = 0; kc < 12; ++kc) {
                        bf16x8 a0 = zf, a1 = zf;
                        if (av0) a0 = *(const bf16x8*)(hr0 + kc * 32);
                        if (do2 && av1) a1 = *(const bf16x8*)(hr1 + kc * 32);
                        bf16x8 bR = *(const bf16x8*)(lwr + (12 + kc) * 512);
                        bf16x8 bZ = *(const bf16x8*)(lwr + 12288 + (12 + kc) * 512);
                        bf16x8 bN = *(const bf16x8*)(lwr + 24576 + (12 + kc) * 512);
                        x.r[0] = __builtin_amdgcn_mfma_f32_16x16x32_bf16(a0, bR, x.r[0], 0, 0, 0);
                        x.z[0] = __builtin_amdgcn_mfma_f32_16x16x32_bf16(a0, bZ, x.z[0], 0, 0, 0);
                        n2a    = __builtin_amdgcn_mfma_f32_16x16x32_bf16(a0, bN, n2a, 0, 0, 0);
                        if (do2) {
                            x.r[1] = __builtin_amdgcn_mfma_f32_16x16x32_bf16(a1, bR, x.r[1], 0, 0, 0);
                            x.z[1] = __builtin_amdgcn_mfma_f32_16x16x32_bf16(a1, bZ, x.z[1], 0, 0, 0);
                            n2b    = __builtin_amdgcn_mfma_f32_16x16x32_bf16(a1, bN, n2b, 0, 0, 0);
                        }
                    }
                }
#pragma unroll
                for (int mt = 0; mt < 2; ++mt) {
                    if (mt && !do2) break;
                    const f32x4 ar = x.r[mt], az = x.z[mt], an1 = x.n[mt];
                    const f32x4 an2 = mt ? n2b : n2a;
#pragma unroll
                    for (int r = 0; r < 4; ++r) {
                        const int m = m0 + mt * 16 + quad * 4 + r;
                        if (m < P) {
                            float rv = sigmoid_(ar[r] + br);
                            float zv = sigmoid_(az[r] + bz);
                            float nv = tanh_(an1[r] + bi + rv * (an2[r] + bh));
                            float hn = (1.0f - zv) * nv + zv * hp[mt][r];
                            hp[mt][r] = hn;
                            hs[mt][r] += hn;
                            if (last) {
                                const size_t idx = (size_t)m * 384 + d;
                                float xo = hs[mt][r] * 0.125f;
                                st_sc1_u16(&Xout[idx], to_bf16(xo));
                                if (!root) st_sc1_f32(&Hfout[idx], hn);
                                else if (m == 0) out[d] = xo;
                            } else {
                                stage[wave][(mt * 16 + quad * 4 + r) * 24 + col] = to_bf16(hn);
                            }
                        }
                    }
                }
                if (!last) {   // wave-private transpose -> one 16B sc1 store per lane
                    const int row = lane >> 1, half = lane & 1;
                    const int m = m0 + row;
                    if (m < P) {
                        bf16x8 v = *(const bf16x8*)&stage[wave][row * 24 + half * 8];
                        st_sc1_b128(HBn + (size_t)m * 384 + ds * 16 + half * 8, v);
                    }
                }
            };

            if (!leaf) {
                if (hasA) prol(mpA, hpA);
                if (hasB) prol(mpB, hpB);
                group_arrive(&ctr[CI((lvl * 9 + 8) * NSLOT + slot)]);
                if (hasA) xpart(mpA, 7, xA);     // t=0 x-half under the barrier
                if (hasB) xpart(mpB, 7, xB);
                group_wait(&ctr[CI((lvl * 9 + 8) * NSLOT + slot)]);
            } else {
                if (hasA) xpart(mpA, 7, xA);
                if (hasB) xpart(mpB, 7, xB);
            }
#pragma unroll 1
            for (int t = 0; t < 8; ++t) {
                const ushort* HBp = HBlvl + (size_t)t * N;
                ushort*       HBn = HBlvl + (size_t)(t + 1) * N;
                const bool hz   = leaf && (t == 0);
                const bool last = (t == 7);
                if (hasA) hpart(mpA, xA, hpA, hsA, HBp, HBn, hz, last);
                if (hasB) hpart(mpB, xB, hpB, hsB, HBp, HBn, hz, last);
                if (!last) {
                    unsigned int* c = &ctr[CI((lvl * 9 + t) * NSLOT + slot)];
                    group_arrive(c);
                    const int nchild = 6 - t;    // next step's x-half under the barrier
                    if (hasA) xpart(mpA, nchild, xA);
                    if (hasB) xpart(mpB, nchild, xB);
                    group_wait(c);
                }
            }
        }
        if (lvl < 4) full_barrier(&ctr[CI(720 + lvl * NSLOT + slot)], &ctr[CI(784 + lvl)]);
    }
}

extern "C" void kernel_launch(void* const* d_in, const int* in_sizes, int n_in,
                              void* d_out, int out_size, void* d_ws, size_t ws_size,
                              hipStream_t stream) {
    const int*   tok   = (const int*)d_in[0];
    const float* table = (const float*)d_in[1];
    const float* w_ih  = (const float*)d_in[2];
    const float* w_hh  = (const float*)d_in[3];
    const float* b_ih  = (const float*)d_in[4];
    const float* b_hh  = (const float*)d_in[5];
    float* out = (float*)d_out;

    char* ws = (char*)d_ws;
    size_t off = 0;
    auto alloc = [&](size_t bytes) -> void* {
        void* p = ws + off;
        off = (off + bytes + 255) & ~(size_t)255;
        return p;
    };
    // total rows across levels: 4096+512+64+8+1 = 4681
    ushort* wswz = (ushort*)alloc((size_t)1152 * 768 * 2);      // swizzled weights
    ushort* XA   = (ushort*)alloc((size_t)32768 * 384 * 2);     // leaf x (bf16)
    ushort* HBar = (ushort*)alloc((size_t)9 * 4681 * 384 * 2);  // per-level 9 fresh h slots
    float*  Hfar = (float*)alloc((size_t)4680 * 384 * 4);       // per-level final h (lvl 0..3)
    ushort* Xoar = (ushort*)alloc((size_t)4681 * 384 * 2);      // per-level output x
    unsigned int* ctr = (unsigned int*)alloc((size_t)NCTR * 32 * 4);

    prep_w<<<(1152 * 96 + 255) / 256, 256, 0, stream>>>(w_ih, w_hh, wswz, ctr);
    embed_gather<<<(32768 * 48 + 255) / 256, 256, 0, stream>>>(tok, table, XA, 32768);
    tree_gru<<<dim3(NBLK), 256, 0, stream>>>(XA, wswz, b_ih, b_hh,
                                             HBar, Hfar, Xoar, ctr, out);
}

// Round 10
// 624.719 us; speedup vs baseline: 1.1958x; 1.0162x over previous
//
#include <hip/hip_runtime.h>
#include <hip/hip_bf16.h>
#include <stdint.h>

typedef float f32x4 __attribute__((ext_vector_type(4)));
typedef short bf16x8 __attribute__((ext_vector_type(8)));

#define NSLOT 16                 // row-slot groups
#define NDS 24                   // gate-dim slices per slot
#define NBLK (NSLOT * NDS)       // 384 blocks, 2/CU -> all co-resident
// counters: 720 step-barriers (5 lvl x 9 idx x 16 slot) + 64 boundary-group + 4 boundary-master
#define NCTR 788
#define CI(i) ((i) * 32)   // pad counters to separate 128B lines

__device__ __forceinline__ ushort to_bf16(float f) {
    union { float f; uint32_t u; } v; v.f = f;
    uint32_t u = v.u;
    return (ushort)((u + 0x7fffu + ((u >> 16) & 1u)) >> 16);   // RNE
}
__device__ __forceinline__ float sigmoid_(float x) { return 1.0f / (1.0f + __expf(-x)); }
__device__ __forceinline__ float tanh_(float x)    { return 1.0f - 2.0f / (__expf(2.0f * x) + 1.0f); }

// Device-scope write-through stores: land at the Infinity Cache coherence
// point, leave no dirty L2 line behind. (Proven rounds 2/5/6/7/9.)
__device__ __forceinline__ void st_sc1_u16(ushort* p, ushort v) {
    asm volatile("global_store_short %0, %1, off sc1" :: "v"(p), "v"((uint32_t)v) : "memory");
}
__device__ __forceinline__ void st_sc1_f32(float* p, float v) {
    asm volatile("global_store_dword %0, %1, off sc1" :: "v"(p), "v"(v) : "memory");
}
__device__ __forceinline__ void st_sc1_b128(void* p, bf16x8 v) {
    asm volatile("global_store_dwordx4 %0, %1, off sc1" :: "v"(p), "v"(v) : "memory");
}

// Swizzled concat weight W'[g][k] = (k<384 ? w_ih : w_hh), bf16; fragment layout:
// elem ((tile*24 + kc)*64 + quad*16 + (g&15))*8 + j  for k = kc*32 + quad*8 + j
__global__ void prep_w(const float* __restrict__ w_ih, const float* __restrict__ w_hh,
                       ushort* __restrict__ wswz, unsigned int* __restrict__ ctr) {
    int tid = blockIdx.x * blockDim.x + threadIdx.x;   // 1152 * 96
    if (tid < NCTR * 32) ctr[tid] = 0u;                // re-zero barrier counters each replay
    if (tid >= 1152 * 96) return;
    int g  = tid / 96;
    int k  = (tid % 96) * 8;
    int kc = k >> 5;
    int q  = (k >> 3) & 3;
    int tile = g >> 4;
    int lane = q * 16 + (g & 15);
    ushort* dst = wswz + ((size_t)(tile * 24 + kc) * 64 + lane) * 8;
    const float* src = (k < 384) ? (w_ih + (size_t)g * 384 + k)
                                 : (w_hh + (size_t)g * 384 + (k - 384));
#pragma unroll
    for (int j = 0; j < 8; ++j) dst[j] = to_bf16(src[j]);
}

__global__ void embed_gather(const int* __restrict__ tok, const float* __restrict__ table,
                             ushort* __restrict__ xleaf, int n_leaves) {
    int tid = blockIdx.x * blockDim.x + threadIdx.x;   // n_leaves * 48
    if (tid >= n_leaves * 48) return;
    int leaf = tid / 48, i = tid % 48;
    const float* src = table + (size_t)tok[leaf] * 384 + i * 8;
    bf16x8 v;
#pragma unroll
    for (int j = 0; j < 8; ++j) v[j] = (short)to_bf16(src[j]);
    *(bf16x8*)(xleaf + (size_t)leaf * 384 + i * 8) = v;
}

// Tight poll (step barriers, 24 pollers/line): atomic fetch_add(0) executes at
// the coherence point -> exact current value every poll (proven r7/r9).
__device__ __forceinline__ void wait_ge(unsigned int* c, unsigned int n) {
    while (__hip_atomic_fetch_add(c, 0u, __ATOMIC_RELAXED, __HIP_MEMORY_SCOPE_AGENT) < n)
        __builtin_amdgcn_s_sleep(1);
}
// Coarse poll (level boundaries): during lvl2-4, up to 360 idle blocks spin
// the single master line. Tight RMW spinning there floods the IF atomic
// pipeline that the ACTIVE slot's latency-critical step-barrier RMWs share
// (suspected cause of tail steps costing as much as full-width steps).
// s_sleep(127) ~ 3.4us granularity: detection latency acceptable at 4
// boundaries; standing RMW pressure cut ~10x.
__device__ __forceinline__ void wait_ge_coarse(unsigned int* c, unsigned int n) {
    while (__hip_atomic_fetch_add(c, 0u, __ATOMIC_RELAXED, __HIP_MEMORY_SCOPE_AGENT) < n)
        __builtin_amdgcn_s_sleep(127);
}

// Group barrier among the 24 ds-blocks of one row-slot, split into arrive /
// wait so independent work (next-step x loads + x-half MFMAs) runs inside
// the wait window. Arrive RMW is RELAXED (r9: -130us vs RELEASE): the
// __syncthreads() drains vmcnt(0), and sc1 write-through stores retire vmcnt
// only when ACK'd at the IF coherence point -> all h-lines globally visible
// before the flag bump; no dirty L2 lines exist, so the release's wbl2 walk
// bought nothing.
__device__ __forceinline__ void group_arrive(unsigned int* c) {
    __syncthreads();   // s_waitcnt vmcnt(0) lgkmcnt(0) + s_barrier
    if (threadIdx.x == 0)
        __hip_atomic_fetch_add(c, 1u, __ATOMIC_RELAXED, __HIP_MEMORY_SCOPE_AGENT);
}
__device__ __forceinline__ void group_wait(unsigned int* c) {
    if (threadIdx.x == 0) wait_ge(c, NDS);
    __syncthreads();
}

// Hierarchical full-grid barrier (384 blocks): 24 arrivals per slot-group,
// last of each group bumps master; everyone polls (coarse) on master == NSLOT.
// r10: arrivals demoted RELEASE -> RELAXED by the same r9 safety argument
// (entry __syncthreads drains vmcnt; sc1 stores already ACK'd at IF), removing
// 1536 buffer_wbl2 L2 walks at the 4 boundaries.
__device__ __forceinline__ void full_barrier(unsigned int* grpSlot, unsigned int* master) {
    __syncthreads();
    if (threadIdx.x == 0) {
        unsigned int old = __hip_atomic_fetch_add(grpSlot, 1u, __ATOMIC_RELAXED, __HIP_MEMORY_SCOPE_AGENT);
        if (old == NDS - 1)
            __hip_atomic_fetch_add(master, 1u, __ATOMIC_RELAXED, __HIP_MEMORY_SCOPE_AGENT);
        wait_ge_coarse(master, NSLOT);
    }
    __syncthreads();
}

// One persistent kernel for the whole tree. 384 blocks x 256 thr, ~78 KB LDS
// -> 2 blocks/CU, all co-resident. Block l: slot = (l&7)*2 + (l>>3)/24,
// ds = (l>>3)%24 -> under round-robin dispatch (xcd = l%8) all 24 ds-blocks
// of a slot land on ONE XCD (verified round 6: FETCH_SIZE 243->49 MB).
// Slot owns m-pairs slot*4+wave (+64). h_prev / running sum in registers;
// bf16 h exchanged via per-step FRESH buffers (no stale cache copies).
__global__ __launch_bounds__(256, 2)
void tree_gru(const ushort* __restrict__ XA, const ushort* __restrict__ W,
              const float* __restrict__ b_ih, const float* __restrict__ b_hh,
              ushort* __restrict__ HBar, float* __restrict__ Hfar,
              ushort* __restrict__ Xoar,
              unsigned int* __restrict__ ctr, float* __restrict__ out)
{
    __shared__ __align__(16) ushort lw[36864];     // weight slice, 72 KB
    __shared__ __align__(16) ushort stage[4][768]; // h-transpose staging, 6 KB (24-stride)
    const int l = blockIdx.x;
    const int dr = l >> 3;                  // 0..47
    const int slot = (l & 7) * 2 + (dr / 24);
    const int ds = dr % 24;
    const int tid = threadIdx.x;
    const int wave = tid >> 6, lane = tid & 63;
    const int quad = lane >> 4, col = lane & 15;
    const int d = ds * 16 + col;

    // Stage this block's weight slice (tiles ds, 24+ds, 48+ds) into LDS - once
    // for the whole tree (all steps, all levels).
    {
        bf16x8* dstv = (bf16x8*)lw;
#pragma unroll
        for (int g = 0; g < 3; ++g) {
            const bf16x8* s = (const bf16x8*)(W + (size_t)(g * NDS + ds) * 12288);
#pragma unroll
            for (int i = 0; i < 6; ++i) dstv[g * 1536 + i * 256 + tid] = s[i * 256 + tid];
        }
    }
    __syncthreads();

    const float br = b_ih[d] + b_hh[d];
    const float bz = b_ih[384 + d] + b_hh[384 + d];
    const float bi = b_ih[768 + d], bh = b_hh[768 + d];
    const ushort* lwr = &lw[(size_t)lane * 8];

#pragma unroll 1
    for (int lvl = 0; lvl < 5; ++lvl) {
        const int P  = (lvl == 0) ? 4096 : (lvl == 1) ? 512 : (lvl == 2) ? 64 : (lvl == 3) ? 8 : 1;
        const int rp = (lvl == 0) ? 0 : (lvl == 1) ? 4096 : (lvl == 2) ? 4608 : (lvl == 3) ? 4672 : 4680;
        const int rpPrev = (lvl == 1) ? 0 : (lvl == 2) ? 4096 : (lvl == 3) ? 4608 : 4672;
        const int nmp = (P + 31) >> 5;          // 32-row m-pairs
        const bool leaf = (lvl == 0), root = (lvl == 4);
        const ushort* Xc = leaf ? XA : (Xoar + (size_t)384 * rpPrev);
        const float* Hfprev = leaf ? nullptr : (Hfar + (size_t)384 * rpPrev);
        ushort* HBlvl = HBar + (size_t)9 * 384 * rp;   // 9 fresh h slots this level
        ushort* Xout  = Xoar + (size_t)384 * rp;
        float*  Hfout = root ? nullptr : (Hfar + (size_t)384 * rp);
        const size_t N = (size_t)P * 384;
        const bool act = (slot * 4 < nmp);             // uniform per slot-group
        if (act) {
            const int mpA = slot * 4 + wave;
            const int mpB = mpA + NSLOT * 4;
            const bool hasA = mpA < nmp;
            const bool hasB = mpB < nmp;
            float hpA[2][4], hsA[2][4], hpB[2][4], hsB[2][4];
#pragma unroll
            for (int mt = 0; mt < 2; ++mt)
#pragma unroll
                for (int r = 0; r < 4; ++r) {
                    hpA[mt][r] = 0.f; hsA[mt][r] = 0.f;
                    hpB[mt][r] = 0.f; hsB[mt][r] = 0.f;
                }
            const f32x4 z4 = (f32x4){0.f, 0.f, 0.f, 0.f};
            const bf16x8 zf = (bf16x8){0, 0, 0, 0, 0, 0, 0, 0};
            struct XA6 { f32x4 r[2], z[2], n[2]; } xA, xB;

            // x-half MFMAs (independent of h) — runs inside barrier-wait windows.
            auto xpart = [&](int mp, int child, XA6& o) {
                const int m0 = mp * 32;
                const bool do2 = (m0 + 16) < P;
                const int par0 = m0 + col, par1 = m0 + 16 + col;
                const bool av0 = par0 < P, av1 = par1 < P;
                const ushort* xr0 = Xc + ((size_t)par0 * 8 + child) * 384 + quad * 8;
                const ushort* xr1 = Xc + ((size_t)par1 * 8 + child) * 384 + quad * 8;
                o.r[0] = z4; o.z[0] = z4; o.n[0] = z4;
                o.r[1] = z4; o.z[1] = z4; o.n[1] = z4;
#pragma unroll
                for (int kc = 0; kc < 12; ++kc) {
                    bf16x8 a0 = zf, a1 = zf;
                    if (av0) a0 = *(const bf16x8*)(xr0 + kc * 32);
                    if (do2 && av1) a1 = *(const bf16x8*)(xr1 + kc * 32);
                    bf16x8 bR = *(const bf16x8*)(lwr + kc * 512);
                    bf16x8 bZ = *(const bf16x8*)(lwr + 12288 + kc * 512);
                    bf16x8 bN = *(const bf16x8*)(lwr + 24576 + kc * 512);
                    o.r[0] = __builtin_amdgcn_mfma_f32_16x16x32_bf16(a0, bR, o.r[0], 0, 0, 0);
                    o.z[0] = __builtin_amdgcn_mfma_f32_16x16x32_bf16(a0, bZ, o.z[0], 0, 0, 0);
                    o.n[0] = __builtin_amdgcn_mfma_f32_16x16x32_bf16(a0, bN, o.n[0], 0, 0, 0);
                    if (do2) {
                        o.r[1] = __builtin_amdgcn_mfma_f32_16x16x32_bf16(a1, bR, o.r[1], 0, 0, 0);
                        o.z[1] = __builtin_amdgcn_mfma_f32_16x16x32_bf16(a1, bZ, o.z[1], 0, 0, 0);
                        o.n[1] = __builtin_amdgcn_mfma_f32_16x16x32_bf16(a1, bN, o.n[1], 0, 0, 0);
                    }
                }
            };
            // h0 = mean of children's final h; publish bf16 to slot 0.
            auto prol = [&](int mp, float (&hp)[2][4]) {
                const int m0 = mp * 32;
#pragma unroll
                for (int mt = 0; mt < 2; ++mt)
#pragma unroll
                    for (int r = 0; r < 4; ++r) {
                        const int m = m0 + mt * 16 + quad * 4 + r;
                        if (m < P) {
                            const float* hc = Hfprev + (size_t)m * 8 * 384 + d;
                            float h0 = 0.f;
#pragma unroll
                            for (int c = 0; c < 8; ++c) h0 += hc[(size_t)c * 384];
                            h0 *= 0.125f;
                            hp[mt][r] = h0;
                            st_sc1_u16(&HBlvl[(size_t)m * 384 + d], to_bf16(h0));
                        }
                    }
            };
            // h-half MFMAs + gate update + vectorized h publish via LDS transpose.
            auto hpart = [&](int mp, XA6& x, float (&hp)[2][4], float (&hs)[2][4],
                             const ushort* HBp, ushort* HBn, bool hz, bool last) {
                const int m0 = mp * 32;
                const bool do2 = (m0 + 16) < P;
                const int par0 = m0 + col, par1 = m0 + 16 + col;
                const bool av0 = par0 < P, av1 = par1 < P;
                f32x4 n2a = z4, n2b = z4;
                if (!hz) {
                    const ushort* hr0 = HBp + (size_t)par0 * 384 + quad * 8;
                    const ushort* hr1 = HBp + (size_t)par1 * 384 + quad * 8;
#pragma unroll
                    for (int kc = 0; kc < 12; ++kc) {
                        bf16x8 a0 = zf, a1 = zf;
                        if (av0) a0 = *(const bf16x8*)(hr0 + kc * 32);
                        if (do2 && av1) a1 = *(const bf16x8*)(hr1 + kc * 32);
                        bf16x8 bR = *(const bf16x8*)(lwr + (12 + kc) * 512);
                        bf16x8 bZ = *(const bf16x8*)(lwr + 12288 + (12 + kc) * 512);
                        bf16x8 bN = *(const bf16x8*)(lwr + 24576 + (12 + kc) * 512);
                        x.r[0] = __builtin_amdgcn_mfma_f32_16x16x32_bf16(a0, bR, x.r[0], 0, 0, 0);
                        x.z[0] = __builtin_amdgcn_mfma_f32_16x16x32_bf16(a0, bZ, x.z[0], 0, 0, 0);
                        n2a    = __builtin_amdgcn_mfma_f32_16x16x32_bf16(a0, bN, n2a, 0, 0, 0);
                        if (do2) {
                            x.r[1] = __builtin_amdgcn_mfma_f32_16x16x32_bf16(a1, bR, x.r[1], 0, 0, 0);
                            x.z[1] = __builtin_amdgcn_mfma_f32_16x16x32_bf16(a1, bZ, x.z[1], 0, 0, 0);
                            n2b    = __builtin_amdgcn_mfma_f32_16x16x32_bf16(a1, bN, n2b, 0, 0, 0);
                        }
                    }
                }
#pragma unroll
                for (int mt = 0; mt < 2; ++mt) {
                    if (mt && !do2) break;
                    const f32x4 ar = x.r[mt], az = x.z[mt], an1 = x.n[mt];
                    const f32x4 an2 = mt ? n2b : n2a;
#pragma unroll
                    for (int r = 0; r < 4; ++r) {
                        const int m = m0 + mt * 16 + quad * 4 + r;
                        if (m < P) {
                            float rv = sigmoid_(ar[r] + br);
                            float zv = sigmoid_(az[r] + bz);
                            float nv = tanh_(an1[r] + bi + rv * (an2[r] + bh));
                            float hn = (1.0f - zv) * nv + zv * hp[mt][r];
                            hp[mt][r] = hn;
                            hs[mt][r] += hn;
                            if (last) {
                                const size_t idx = (size_t)m * 384 + d;
                                float xo = hs[mt][r] * 0.125f;
                                st_sc1_u16(&Xout[idx], to_bf16(xo));
                                if (!root) st_sc1_f32(&Hfout[idx], hn);
                                else if (m == 0) out[d] = xo;
                            } else {
                                stage[wave][(mt * 16 + quad * 4 + r) * 24 + col] = to_bf16(hn);
                            }
                        }
                    }
                }
                if (!last) {   // wave-private transpose -> one 16B sc1 store per lane
                    const int row = lane >> 1, half = lane & 1;
                    const int m = m0 + row;
                    if (m < P) {
                        bf16x8 v = *(const bf16x8*)&stage[wave][row * 24 + half * 8];
                        st_sc1_b128(HBn + (size_t)m * 384 + ds * 16 + half * 8, v);
                    }
                }
            };

            if (!leaf) {
                if (hasA) prol(mpA, hpA);
                if (hasB) prol(mpB, hpB);
                group_arrive(&ctr[CI((lvl * 9 + 8) * NSLOT + slot)]);
                if (hasA) xpart(mpA, 7, xA);     // t=0 x-half under the barrier
                if (hasB) xpart(mpB, 7, xB);
                group_wait(&ctr[CI((lvl * 9 + 8) * NSLOT + slot)]);
            } else {
                if (hasA) xpart(mpA, 7, xA);
                if (hasB) xpart(mpB, 7, xB);
            }
#pragma unroll 1
            for (int t = 0; t < 8; ++t) {
                const ushort* HBp = HBlvl + (size_t)t * N;
                ushort*       HBn = HBlvl + (size_t)(t + 1) * N;
                const bool hz   = leaf && (t == 0);
                const bool last = (t == 7);
                if (hasA) hpart(mpA, xA, hpA, hsA, HBp, HBn, hz, last);
                if (hasB) hpart(mpB, xB, hpB, hsB, HBp, HBn, hz, last);
                if (!last) {
                    unsigned int* c = &ctr[CI((lvl * 9 + t) * NSLOT + slot)];
                    group_arrive(c);
                    const int nchild = 6 - t;    // next step's x-half under the barrier
                    if (hasA) xpart(mpA, nchild, xA);
                    if (hasB) xpart(mpB, nchild, xB);
                    group_wait(c);
                }
            }
        }
        if (lvl < 4) full_barrier(&ctr[CI(720 + lvl * NSLOT + slot)], &ctr[CI(784 + lvl)]);
    }
}

extern "C" void kernel_launch(void* const* d_in, const int* in_sizes, int n_in,
                              void* d_out, int out_size, void* d_ws, size_t ws_size,
                              hipStream_t stream) {
    const int*   tok   = (const int*)d_in[0];
    const float* table = (const float*)d_in[1];
    const float* w_ih  = (const float*)d_in[2];
    const float* w_hh  = (const float*)d_in[3];
    const float* b_ih  = (const float*)d_in[4];
    const float* b_hh  = (const float*)d_in[5];
    float* out = (float*)d_out;

    char* ws = (char*)d_ws;
    size_t off = 0;
    auto alloc = [&](size_t bytes) -> void* {
        void* p = ws + off;
        off = (off + bytes + 255) & ~(size_t)255;
        return p;
    };
    // total rows across levels: 4096+512+64+8+1 = 4681
    ushort* wswz = (ushort*)alloc((size_t)1152 * 768 * 2);      // swizzled weights
    ushort* XA   = (ushort*)alloc((size_t)32768 * 384 * 2);     // leaf x (bf16)
    ushort* HBar = (ushort*)alloc((size_t)9 * 4681 * 384 * 2);  // per-level 9 fresh h slots
    float*  Hfar = (float*)alloc((size_t)4680 * 384 * 4);       // per-level final h (lvl 0..3)
    ushort* Xoar = (ushort*)alloc((size_t)4681 * 384 * 2);      // per-level output x
    unsigned int* ctr = (unsigned int*)alloc((size_t)NCTR * 32 * 4);

    prep_w<<<(1152 * 96 + 255) / 256, 256, 0, stream>>>(w_ih, w_hh, wswz, ctr);
    embed_gather<<<(32768 * 48 + 255) / 256, 256, 0, stream>>>(tok, table, XA, 32768);
    tree_gru<<<dim3(NBLK), 256, 0, stream>>>(XA, wswz, b_ih, b_hh,
                                             HBar, Hfar, Xoar, ctr, out);
}